// Round 13
// baseline (371.927 us; speedup 1.0000x reference)
//
#include <hip/hip_runtime.h>
#include <hip/hip_bf16.h>
#include <stdint.h>

#define DIM 512
#define NROWS 1024
#define NCLS 100000
#define NST 391                         // stripes of 256 cols
#define NCLS_PAD (NST * 256)            // 100096
#define SCALE_S 64.0f
#define S_LOG2E 92.332482616893662f     // 64 * log2(e)

typedef __attribute__((ext_vector_type(8))) __bf16 bf16x8;
typedef __attribute__((ext_vector_type(4))) float f32x4;

__device__ __forceinline__ unsigned short f2bf(float x) {
  __hip_bfloat16 h = __float2bfloat16(x);
  union { __hip_bfloat16 h; unsigned short u; } v; v.h = h; return v.u;
}
__device__ __forceinline__ unsigned pack2(float a, float b) {
  return ((unsigned)f2bf(b) << 16) | (unsigned)f2bf(a);
}
__device__ __forceinline__ void async_ld16(const void* g, void* l) {
  __builtin_amdgcn_global_load_lds((const __attribute__((address_space(1))) void*)g,
                                   (__attribute__((address_space(3))) void*)l, 16, 0, 0);
}

// ---------------- kernel 1a: normalize inputs -> bf16 ----------------
__global__ void prep_a(const float* __restrict__ X, unsigned short* __restrict__ A16,
                       float* __restrict__ xnorm) {
  const int row = blockIdx.x;
  const int lane = threadIdx.x;  // 64
  const float4* xp = (const float4*)(X + (size_t)row * DIM);
  float4 v0 = xp[lane];
  float4 v1 = xp[lane + 64];
  float ss = v0.x*v0.x + v0.y*v0.y + v0.z*v0.z + v0.w*v0.w
           + v1.x*v1.x + v1.y*v1.y + v1.z*v1.z + v1.w*v1.w;
  #pragma unroll
  for (int m = 1; m < 64; m <<= 1) ss += __shfl_xor(ss, m);
  const float nrm = sqrtf(ss);
  const float inv = 1.0f / fmaxf(nrm, 1e-12f);
  if (lane == 0) xnorm[row] = nrm;
  unsigned short* ap = A16 + (size_t)row * DIM;
  *(uint2*)(ap + lane * 4)       = make_uint2(pack2(v0.x*inv, v0.y*inv), pack2(v0.z*inv, v0.w*inv));
  *(uint2*)(ap + 256 + lane * 4) = make_uint2(pack2(v1.x*inv, v1.y*inv), pack2(v1.z*inv, v1.w*inv));
}

// ---------------- kernel 1b: normalize weight rows -> bf16 (padded to 100096) ----------------
__global__ void prep_w(const float* __restrict__ Wg, unsigned short* __restrict__ W16) {
  const int row = blockIdx.x * 4 + (threadIdx.x >> 6);
  const int lane = threadIdx.x & 63;
  unsigned short* op = W16 + (size_t)row * DIM;
  if (row >= NCLS) {                       // zero-pad tail rows (cos=0 -> exp2(-92)~0)
    *(uint4*)((char*)op + lane * 16) = make_uint4(0, 0, 0, 0);
    return;
  }
  const float4* xp = (const float4*)(Wg + (size_t)row * DIM);
  float4 v0 = xp[lane];
  float4 v1 = xp[lane + 64];
  float ss = v0.x*v0.x + v0.y*v0.y + v0.z*v0.z + v0.w*v0.w
           + v1.x*v1.x + v1.y*v1.y + v1.z*v1.z + v1.w*v1.w;
  #pragma unroll
  for (int m = 1; m < 64; m <<= 1) ss += __shfl_xor(ss, m);
  const float inv = 1.0f / fmaxf(sqrtf(ss), 1e-12f);
  *(uint2*)(op + lane * 4)       = make_uint2(pack2(v0.x*inv, v0.y*inv), pack2(v0.z*inv, v0.w*inv));
  *(uint2*)(op + 256 + lane * 4) = make_uint2(pack2(v1.x*inv, v1.y*inv), pack2(v1.z*inv, v1.w*inv));
}

// ---------------- kernel 2: 256x256 tile, BK=32, 4-slot LDS ring ----------------
// 512 threads, 8 waves (2M x 4N): wave output 128x64. Per K-step(32) per wave:
// 32 MFMA, LDS reads A8+B4 (12KB) -> 375 B/MFMA (vs 512 in the 128-tile shape).
// Ring of 4 slots x 32KB (A16KB+B16KB). K-step t: stage t+2 (4 gload_lds/thread),
// ONE s_waitcnt vmcnt(8) + ONE barrier. FIFO proof: outstanding at t's wait =
// t(4, issued t-2) + t+1(4, issued t-1) + t+2(4, just issued) = 12; vmcnt(8)
// drains exactly t's 4 -> slot t proven staged, 2 K-steps of prefetch stay in
// flight. Ring-4 race-free with wave skew <=1: slots t,t+1,t+2,t+3 distinct.
// acc[8][4] AGPR-anchored (r10-proven); per-phase arch set ~70 regs.
// LDS 64B rows swizzled byte ^= ((r>>1)&3)<<4: rows 0..7 cover all 32 banks.

__global__ __launch_bounds__(512, 1) void gemm_lse5(
    const unsigned short* __restrict__ A16, const unsigned short* __restrict__ W16,
    float* __restrict__ part_s) {
  __shared__ char lds[4 * 32768];
  const int tid = threadIdx.x;
  const int lane = tid & 63;
  const int wave = tid >> 6;               // 0..7
  const int lr = lane & 15, lg = lane >> 4;
  const int wr = wave >> 2;                // M half 0..1
  const int wn = wave & 3;                 // N quarter 0..3

  // bid -> (mblk, nblk): 4 mblks of one stripe-column share XCD (bid&7)
  const int bid = blockIdx.x;              // 256 blocks
  const int x = bid & 7;
  const int q = bid >> 3;
  const int mblk = q & 3;
  const int nblk = x * 8 + (q >> 2);       // 0..63
  const int mrow0 = mblk * 256;

  const char* Ag = (const char*)A16 + (size_t)mrow0 * 1024;
  const char* Wg = (const char*)W16;

  // ds_read byte offsets within a slot (A region [256 r][64B], B at +16384)
  unsigned offA[8], offB[4];
  #pragma unroll
  for (int mi = 0; mi < 8; ++mi) {
    const int r = wr * 128 + mi * 16 + lr;
    offA[mi] = r * 64 + ((lg * 16) ^ (((r >> 1) & 3) << 4));
  }
  #pragma unroll
  for (int ni = 0; ni < 4; ++ni) {
    const int c = wn * 64 + ni * 16 + lr;
    offB[ni] = 16384 + c * 64 + ((lg * 16) ^ (((c >> 1) & 3) << 4));
  }

  // staging: load i in {0,1}: LDS dest (wave*2+i)*1024 (uniform) + HW lane*16.
  // source row/slot for this lane, pre-swizzled so swizzled ds_read sees
  // logical bytes (inverse == same XOR, 16B-slot granular).
  unsigned arel[2], brel[2], dstO[2];
  #pragma unroll
  for (int i = 0; i < 2; ++i) {
    const int d = (wave * 2 + i) * 1024 + lane * 16;
    const int r = d >> 6;                  // row/col index 0..255
    const int sl = d & 63;                 // 16B-aligned slot in 64B row
    const unsigned srel = (unsigned)r * 1024 + (sl ^ (((r >> 1) & 3) << 4));
    arel[i] = srel; brel[i] = srel;        // same pattern for A and B
    dstO[i] = (unsigned)(wave * 2 + i) * 1024;
  }

  f32x4 acc[8][4];
  #pragma unroll
  for (int mi = 0; mi < 8; ++mi)
    #pragma unroll
    for (int ni = 0; ni < 4; ++ni) acc[mi][ni] = f32x4{0.f, 0.f, 0.f, 0.f};
  float srow[8][4];
  #pragma unroll
  for (int mi = 0; mi < 8; ++mi)
    #pragma unroll
    for (int r = 0; r < 4; ++r) srow[mi][r] = 0.f;

  const int nstr = (NST - nblk + 63) / 64;     // 6 or 7 stripes
  const int ntiles = nstr * 16;                // K-steps total (BK=32, 16/stripe)

  // stage K-step t into slot t&3 (4 loads: A x2, B x2)
  #define STAGE(T, SLOT)                                                           \
    do {                                                                           \
      const long c0_ = ((long)nblk + (long)((T) >> 4) * 64) * 256;                 \
      const unsigned ko_ = (unsigned)((T) & 15) * 64;                              \
      char* sb_ = lds + (SLOT) * 32768;                                            \
      const char* wb_ = Wg + c0_ * 1024;                                           \
      async_ld16(Ag + arel[0] + ko_, sb_ + dstO[0]);                               \
      async_ld16(Ag + arel[1] + ko_, sb_ + dstO[1]);                               \
      async_ld16(wb_ + brel[0] + ko_, sb_ + 16384 + dstO[0]);                      \
      async_ld16(wb_ + brel[1] + ko_, sb_ + 16384 + dstO[1]);                      \
    } while (0)

  // prologue: K-steps 0,1
  STAGE(0, 0);
  STAGE(1, 1);

  #define STEPK(TBASE, SL)                                                         \
    do {                                                                           \
      const int t_ = (TBASE) + (SL);                                               \
      if (t_ + 2 < ntiles) {                                                       \
        STAGE(t_ + 2, ((SL) + 2) & 3);                                             \
        asm volatile("s_waitcnt vmcnt(8)" ::: "memory");                           \
      } else {                                                                     \
        asm volatile("s_waitcnt vmcnt(0)" ::: "memory");                           \
      }                                                                            \
      __builtin_amdgcn_s_barrier();                                                \
      const char* sb_ = lds + (SL) * 32768;                                        \
      bf16x8 bfr_[4];                                                              \
      _Pragma("unroll")                                                            \
      for (int ni = 0; ni < 4; ++ni) bfr_[ni] = *(const bf16x8*)(sb_ + offB[ni]);  \
      _Pragma("unroll")                                                            \
      for (int mh = 0; mh < 2; ++mh) {                                             \
        bf16x8 afr_[4];                                                            \
        _Pragma("unroll")                                                          \
        for (int k = 0; k < 4; ++k) afr_[k] = *(const bf16x8*)(sb_ + offA[mh * 4 + k]); \
        _Pragma("unroll")                                                          \
        for (int k = 0; k < 4; ++k)                                                \
          _Pragma("unroll")                                                        \
          for (int ni = 0; ni < 4; ++ni)                                           \
            acc[mh * 4 + k][ni] = __builtin_amdgcn_mfma_f32_16x16x32_bf16(         \
                afr_[k], bfr_[ni], acc[mh * 4 + k][ni], 0, 0, 0);                  \
      }                                                                            \
      _Pragma("unroll")                                                            \
      for (int mi = 0; mi < 8; ++mi)                                               \
        _Pragma("unroll")                                                          \
        for (int ni = 0; ni < 4; ++ni)                                             \
          asm volatile("" : "+a"(acc[mi][ni]));                                    \
      if ((t_ & 15) == 15) {                                                       \
        _Pragma("unroll")                                                          \
        for (int mi = 0; mi < 8; ++mi)                                             \
          _Pragma("unroll")                                                        \
          for (int ni = 0; ni < 4; ++ni)                                           \
            _Pragma("unroll")                                                      \
            for (int r = 0; r < 4; ++r) {                                          \
              float c_ = fminf(1.f, fmaxf(-1.f, acc[mi][ni][r]));                  \
              srow[mi][r] += exp2f(fmaf(c_, S_LOG2E, -S_LOG2E));                   \
              acc[mi][ni][r] = 0.f;                                                \
            }                                                                      \
      }                                                                            \
    } while (0)

  for (int tb = 0; tb < ntiles; tb += 4) {   // ntiles % 16 == 0
    STEPK(tb, 0);
    STEPK(tb, 1);
    STEPK(tb, 2);
    STEPK(tb, 3);
  }

  // ---- reduce: 16 lr-lanes in-wave, then 4 wn-waves via LDS ----
  float* ldsrow = (float*)lds;               // pipeline done, LDS free
  __builtin_amdgcn_s_barrier();
  #pragma unroll
  for (int mi = 0; mi < 8; ++mi)
    #pragma unroll
    for (int r = 0; r < 4; ++r) {
      float v = srow[mi][r];
      v += __shfl_xor(v, 1); v += __shfl_xor(v, 2);
      v += __shfl_xor(v, 4); v += __shfl_xor(v, 8);
      if (lr == 0)
        ldsrow[wn * 256 + wr * 128 + mi * 16 + lg * 4 + r] = v;
    }
  __builtin_amdgcn_s_barrier();
  asm volatile("s_waitcnt lgkmcnt(0)" ::: "memory");
  if (tid < 256) {
    float v = ldsrow[tid] + ldsrow[256 + tid] + ldsrow[512 + tid] + ldsrow[768 + tid];
    part_s[(size_t)nblk * NROWS + mrow0 + tid] = v;
  }
}

// ---------------- kernel 3: precise f32 target logit + merge partials ----------------
__global__ void finalize_kernel(const float* __restrict__ X, const int* __restrict__ labels,
                                const float* __restrict__ Wg, const float* __restrict__ xnorm,
                                const float* __restrict__ part_s, float* __restrict__ rowloss) {
  const int row = blockIdx.x;
  const int lane = threadIdx.x;   // 64
  const int lbl = labels[row];
  const float4* xp = (const float4*)(X + (size_t)row * DIM);
  const float4* wp = (const float4*)(Wg + (size_t)lbl * DIM);
  float dot = 0.f, wss = 0.f;
  #pragma unroll
  for (int i = 0; i < 2; ++i) {
    float4 xv = xp[lane + 64 * i];
    float4 wv = wp[lane + 64 * i];
    dot += xv.x*wv.x + xv.y*wv.y + xv.z*wv.z + xv.w*wv.w;
    wss += wv.x*wv.x + wv.y*wv.y + wv.z*wv.z + wv.w*wv.w;
  }
  float psum = part_s[(size_t)lane * NROWS + row];   // 64 partials per row
  #pragma unroll
  for (int m = 1; m < 64; m <<= 1) {
    dot += __shfl_xor(dot, m); wss += __shfl_xor(wss, m); psum += __shfl_xor(psum, m);
  }
  if (lane == 0) {
    float c = dot / (fmaxf(xnorm[row], 1e-12f) * fmaxf(sqrtf(wss), 1e-12f));
    c = fminf(1.f, fmaxf(-1.f, c));
    const float cm = 0.99500416527802576610f;   // cos(0.1)
    const float sn = 0.09983341664682815230f;   // sin(0.1)
    float unmod = SCALE_S * c;                  // term the GEMM summed at the label column
    float modv  = SCALE_S * (c * cm - sqrtf(fmaxf(0.f, 1.f - c * c)) * sn); // S*cos(theta+m)
    float stot = psum - __expf(unmod - SCALE_S) + __expf(modv - SCALE_S);
    stot = fmaxf(stot, 1e-37f);
    rowloss[row] = (logf(stot) + SCALE_S) - modv;   // logsumexp - target logit
  }
}

// ---------------- kernel 4: mean over rows ----------------
__global__ void reduce_kernel(const float* __restrict__ rowloss, float* __restrict__ out) {
  const int tid = threadIdx.x;   // 256
  float s = 0.f;
  #pragma unroll
  for (int i = 0; i < 4; ++i) s += rowloss[tid + i * 256];
  #pragma unroll
  for (int m = 1; m < 64; m <<= 1) s += __shfl_xor(s, m);
  __shared__ float wsum[4];
  if ((tid & 63) == 0) wsum[tid >> 6] = s;
  __syncthreads();
  if (tid == 0) out[0] = (wsum[0] + wsum[1] + wsum[2] + wsum[3]) * (1.0f / NROWS);
}

extern "C" void kernel_launch(void* const* d_in, const int* in_sizes, int n_in,
                              void* d_out, int out_size, void* d_ws, size_t ws_size,
                              hipStream_t stream) {
  const float* X      = (const float*)d_in[0];
  const int*   labels = (const int*)d_in[1];
  const float* Wg     = (const float*)d_in[2];
  float* out = (float*)d_out;
  char* ws = (char*)d_ws;
  // ws layout (bytes):
  //   A16    @ 0            1,048,576
  //   W16    @ 1,048,576  102,498,304   (100096 x 512 x 2B, rows >= NCLS zeroed)
  //   part_s @ 103,546,880    262,144   (64 x 1024 x 4B)
  //   xnorm  @ 103,809,024      4,096
  //   rowloss@ 103,813,120      4,096
  unsigned short* A16 = (unsigned short*)ws;
  unsigned short* W16 = (unsigned short*)(ws + 1048576);
  float* part_s  = (float*)(ws + 103546880);
  float* xnorm   = (float*)(ws + 103809024);
  float* rowloss = (float*)(ws + 103813120);

  prep_a<<<NROWS, 64, 0, stream>>>(X, A16, xnorm);
  prep_w<<<NCLS_PAD / 4, 256, 0, stream>>>(Wg, W16);
  gemm_lse5<<<256, 512, 0, stream>>>(A16, W16, part_s);
  finalize_kernel<<<NROWS, 64, 0, stream>>>(X, labels, Wg, xnorm, part_s, rowloss);
  reduce_kernel<<<1, 256, 0, stream>>>(rowloss, out);
}